// Round 18
// baseline (162.400 us; speedup 1.0000x reference)
//
#include <hip/hip_runtime.h>
#include <hip/hip_bf16.h>

// Problem constants
#define NB   64
#define NCDD 5
#define NHIS 100
#define ND   256
#define NK   10
#define TLD  23040          // T*L*D = 30*3*256
#define THRESH 0.1f
#define NEG_INF (-3.402823466e38f)
#define NROWS_HIS 6400      // 64*100
#define NROWS_CDD 320       // 64*5

typedef float f32x4 __attribute__((ext_vector_type(4)));

// ---------------------------------------------------------------------------
// Kernel 1: BYTE-IDENTICAL to R9/R17 (proven).
// ---------------------------------------------------------------------------
__global__ __launch_bounds__(256) void proj_norm_all(
    const float* __restrict__ his_repr,
    const float* __restrict__ cdd_repr,
    const float* __restrict__ W,
    const float* __restrict__ bvec,
    float* __restrict__ Yall)
{
    __shared__ float red[4][8];
    const int r0  = blockIdx.x * 8;
    const int tid = threadIdx.x;
    const int sub = tid & 3;
    const int grp = tid >> 2;
    const int wave = tid >> 6, lane = tid & 63;

    const float* __restrict__ X = (r0 < NROWS_HIS)
        ? (his_repr + (size_t)r0 * ND)
        : (cdd_repr + (size_t)(r0 - NROWS_HIS) * ND);

    float acc[4][8];
#pragma unroll
    for (int p = 0; p < 4; ++p)
#pragma unroll
        for (int r = 0; r < 8; ++r) acc[p][r] = 0.f;

#pragma unroll 4
    for (int i = 0; i < 16; ++i) {
        const int kb = sub * 4 + 16 * i;
        float4 x4[8];
#pragma unroll
        for (int r = 0; r < 8; ++r)
            x4[r] = *(const float4*)(X + (size_t)r * ND + kb);
#pragma unroll
        for (int p = 0; p < 4; ++p) {
            const int d = p * 64 + grp;
            const float4 w4 = *(const float4*)(W + (size_t)d * ND + kb);
#pragma unroll
            for (int r = 0; r < 8; ++r)
                acc[p][r] += w4.x * x4[r].x + w4.y * x4[r].y
                           + w4.z * x4[r].z + w4.w * x4[r].w;
        }
    }

#pragma unroll
    for (int p = 0; p < 4; ++p)
#pragma unroll
        for (int r = 0; r < 8; ++r) {
            float v = acc[p][r];
            v += __shfl_xor(v, 1);
            v += __shfl_xor(v, 2);
            acc[p][r] = v;
        }

    float bias[4];
#pragma unroll
    for (int p = 0; p < 4; ++p) bias[p] = bvec[p * 64 + grp];

    float ss[8];
#pragma unroll
    for (int r = 0; r < 8; ++r) {
        float t = 0.f;
#pragma unroll
        for (int p = 0; p < 4; ++p) {
            const float y = acc[p][r] + bias[p];
            acc[p][r] = y;
            t += y * y;
        }
        for (int off = 32; off; off >>= 1) t += __shfl_xor(t, off);
        ss[r] = t;
    }
    if (lane == 0) {
#pragma unroll
        for (int r = 0; r < 8; ++r) red[wave][r] = ss[r];
    }
    __syncthreads();

#pragma unroll
    for (int r = 0; r < 8; ++r) {
        const float s = 0.25f * (red[0][r] + red[1][r] + red[2][r] + red[3][r]);
        const float scale = 1.0f / fmaxf(sqrtf(s), 1e-12f);
        if (sub == 0) {
#pragma unroll
            for (int p = 0; p < 4; ++p)
                Yall[(size_t)(r0 + r) * ND + p * 64 + grp] = acc[p][r] * scale;
        }
    }
}

// ---------------------------------------------------------------------------
// Kernel 2: R8's proven 64-block/512-thread attn+topk + SORT tail.
// After the 5 top-10s, wave 0 rank-sorts b's 50 picks by (idx, slot) —
// key = idx*50 + t is unique => rank is a bijection — and publishes
// ws_sortedg[b*50 + rank] = b*50 + t. Gather blocks then process same-row
// picks dispatch-adjacent -> duplicate reads hit the 4MB XCD L2.
// ---------------------------------------------------------------------------
__global__ __launch_bounds__(512) void attn_topk_kernel(
    const float* __restrict__ cdd_p,
    const float* __restrict__ his_p,
    float* __restrict__ out_idx_f,
    int* __restrict__ ws_idx,
    float* __restrict__ ws_w,
    int* __restrict__ ws_sortedg)
{
    __shared__ float attn_s[NCDD][128];
    __shared__ int   keys_s[NCDD * NK];
    const int b   = blockIdx.x;
    const int tid = threadIdx.x;
    const int sub = tid & 3, grp = tid >> 2;
    const int wave = tid >> 6, lane = tid & 63;

    const float* __restrict__ cbase = cdd_p + (size_t)b * NCDD * ND;
    const float* __restrict__ hbase = his_p + (size_t)b * NHIS * ND;

#pragma unroll
    for (int it = 0; it < 4; ++it) {
        const int task = it * 128 + grp;
        if (task < NCDD * NHIS) {
            const int c = task / NHIS, h = task - c * NHIS;
            const float* __restrict__ crow = cbase + (size_t)c * ND;
            const float* __restrict__ hrow = hbase + (size_t)h * ND;
            float a = 0.f;
#pragma unroll
            for (int i = 0; i < 16; ++i) {
                const int kb = sub * 4 + 16 * i;
                const float4 cv = *(const float4*)(crow + kb);
                const float4 hv = *(const float4*)(hrow + kb);
                a += cv.x * hv.x + cv.y * hv.y + cv.z * hv.z + cv.w * hv.w;
            }
            a += __shfl_xor(a, 1);
            a += __shfl_xor(a, 2);
            if (sub == 0) attn_s[c][h] = a;
        }
    }
    __syncthreads();

    if (wave < NCDD) {
        const int c = wave;
        float v0 = attn_s[c][lane];
        float v1 = (lane + 64 < NHIS) ? attn_s[c][lane + 64] : NEG_INF;
#pragma unroll
        for (int k = 0; k < NK; ++k) {
            float lv; int li;
            if (v1 > v0) { lv = v1; li = lane + 64; }
            else         { lv = v0; li = lane; }            // tie -> lower idx
            for (int off = 1; off < 64; off <<= 1) {
                const float ov = __shfl_xor(lv, off);
                const int   oi = __shfl_xor(li, off);
                if (ov > lv || (ov == lv && oi < li)) { lv = ov; li = oi; }
            }
            if (lane == 0) {
                const float w = (lv < THRESH) ? 0.0f : lv;
                const int g = (b * NCDD + c) * NK + k;
                ws_idx[g] = li;
                ws_w[g]   = w;
                out_idx_f[g] = (float)li;
                keys_s[c * NK + k] = li * (NCDD * NK) + c * NK + k; // unique
            }
            if (li == lane)            v0 = NEG_INF;
            else if (li == lane + 64)  v1 = NEG_INF;
        }
    }
    __syncthreads();

    // Rank sort (wave 0, lanes 0..49): rank = #{u : key_u < key_t}
    if (wave == 0 && lane < NCDD * NK) {
        const int mykey = keys_s[lane];
        int rank = 0;
        for (int u = 0; u < NCDD * NK; ++u)
            rank += (keys_s[u] < mykey) ? 1 : 0;
        ws_sortedg[b * (NCDD * NK) + rank] = b * (NCDD * NK) + lane;
    }
}

// ---------------------------------------------------------------------------
// Kernel 3: gather + scale — copy body BYTE-IDENTICAL to R9/R17. Only the
// block->output-row mapping changes: slot s within XCD x covers b = x*8+s/50,
// and the row is ws_sortedg[b*50 + s%50] (sorted by picked idx) so duplicate
// source rows are processed dispatch-adjacent on the same XCD -> L2 hits.
// Same blocks, same writes, same partition; pure reorder (bijective).
// ---------------------------------------------------------------------------
__global__ __launch_bounds__(256) void gather_kernel(
    const float* __restrict__ his_emb,
    const int* __restrict__ ws_idx,
    const float* __restrict__ ws_w,
    const int* __restrict__ ws_sortedg,
    float* __restrict__ out)
{
    const int orig = blockIdx.x;
    const int x = orig & 7, s = orig >> 3;          // XCD x, local slot s
    const int b = x * 8 + s / (NCDD * NK);
    const int j = s % (NCDD * NK);
    const int g = ws_sortedg[b * (NCDD * NK) + j];  // sorted-by-idx pick
    const int tid = threadIdx.x;
    const float w = ws_w[g];

    f32x4* __restrict__ dst = (f32x4*)(out + (size_t)g * TLD);

    if (w == 0.0f) {
        const f32x4 z = {0.f, 0.f, 0.f, 0.f};
#pragma unroll
        for (int it = 0; it < 22; ++it) dst[tid + it * 256] = z;
        if (tid < 128) dst[22 * 256 + tid] = z;
        return;
    }

    const int idx = ws_idx[g];
    const f32x4* __restrict__ src =
        (const f32x4*)(his_emb + ((size_t)b * NHIS + idx) * TLD);

    f32x4 v[22];
    f32x4 vt;
#pragma unroll
    for (int j2 = 0; j2 < 22; ++j2) v[j2] = src[tid + j2 * 256];
    const bool tail = (tid < 128);
    if (tail) vt = src[22 * 256 + tid];

#pragma unroll
    for (int j2 = 0; j2 < 22; ++j2) dst[tid + j2 * 256] = v[j2] * w;
    if (tail) dst[22 * 256 + tid] = vt * w;
}

// ---------------------------------------------------------------------------
extern "C" void kernel_launch(void* const* d_in, const int* in_sizes, int n_in,
                              void* d_out, int out_size, void* d_ws, size_t ws_size,
                              hipStream_t stream)
{
    const float* cdd_repr = (const float*)d_in[0];   // (64,5,256)
    const float* his_repr = (const float*)d_in[1];   // (64,100,256)
    const float* his_emb  = (const float*)d_in[2];   // (64,100,30,3,256)
    const float* W_sel    = (const float*)d_in[3];   // (256,256)
    const float* b_sel    = (const float*)d_in[4];   // (256,)
    float* out = (float*)d_out;

    // Workspace layout
    char* ws = (char*)d_ws;
    float* Yall  = (float*)ws;                       // 6720 rows * 256 * 4
    float* his_p = Yall;                             // rows [0, 6400)
    float* cdd_p = Yall + (size_t)NROWS_HIS * ND;    // rows [6400, 6720)
    int*   idx_i = (int*)(ws + 6881280);             // 3200*4
    float* w_w   = (float*)(ws + 6894080);           // 3200*4
    int*   sg_i  = (int*)(ws + 6906880);             // 3200*4 sorted order

    // Output: his_activated [73,728,000] then idx [3200] (as float values)
    float* out_idx_f = out + (size_t)NB * NCDD * NK * TLD;

    proj_norm_all<<<(NROWS_HIS + NROWS_CDD) / 8, 256, 0, stream>>>(
        his_repr, cdd_repr, W_sel, b_sel, Yall);
    attn_topk_kernel<<<NB, 512, 0, stream>>>(cdd_p, his_p,
                                             out_idx_f, idx_i, w_w, sg_i);
    gather_kernel<<<NB * NCDD * NK, 256, 0, stream>>>(his_emb, idx_i, w_w,
                                                      sg_i, out);
}

// Round 19
// 159.879 us; speedup vs baseline: 1.0158x; 1.0158x over previous
//
#include <hip/hip_runtime.h>
#include <hip/hip_bf16.h>

// Problem constants
#define NB   64
#define NCDD 5
#define NHIS 100
#define ND   256
#define NK   10
#define TLD  23040          // T*L*D = 30*3*256
#define THRESH 0.1f
#define NEG_INF (-3.402823466e38f)
#define NROWS_HIS 6400      // 64*100
#define NROWS_CDD 320       // 64*5

typedef float f32x4 __attribute__((ext_vector_type(4)));

// ---------------------------------------------------------------------------
// Kernel 1: projection + L2-norm (R9 body, proven best).
// ---------------------------------------------------------------------------
__global__ __launch_bounds__(256) void proj_norm_all(
    const float* __restrict__ his_repr,
    const float* __restrict__ cdd_repr,
    const float* __restrict__ W,
    const float* __restrict__ bvec,
    float* __restrict__ Yall)
{
    __shared__ float red[4][8];
    const int r0  = blockIdx.x * 8;
    const int tid = threadIdx.x;
    const int sub = tid & 3;
    const int grp = tid >> 2;
    const int wave = tid >> 6, lane = tid & 63;

    const float* __restrict__ X = (r0 < NROWS_HIS)
        ? (his_repr + (size_t)r0 * ND)
        : (cdd_repr + (size_t)(r0 - NROWS_HIS) * ND);

    float acc[4][8];
#pragma unroll
    for (int p = 0; p < 4; ++p)
#pragma unroll
        for (int r = 0; r < 8; ++r) acc[p][r] = 0.f;

#pragma unroll 4
    for (int i = 0; i < 16; ++i) {
        const int kb = sub * 4 + 16 * i;
        float4 x4[8];
#pragma unroll
        for (int r = 0; r < 8; ++r)
            x4[r] = *(const float4*)(X + (size_t)r * ND + kb);
#pragma unroll
        for (int p = 0; p < 4; ++p) {
            const int d = p * 64 + grp;
            const float4 w4 = *(const float4*)(W + (size_t)d * ND + kb);
#pragma unroll
            for (int r = 0; r < 8; ++r)
                acc[p][r] += w4.x * x4[r].x + w4.y * x4[r].y
                           + w4.z * x4[r].z + w4.w * x4[r].w;
        }
    }

#pragma unroll
    for (int p = 0; p < 4; ++p)
#pragma unroll
        for (int r = 0; r < 8; ++r) {
            float v = acc[p][r];
            v += __shfl_xor(v, 1);
            v += __shfl_xor(v, 2);
            acc[p][r] = v;
        }

    float bias[4];
#pragma unroll
    for (int p = 0; p < 4; ++p) bias[p] = bvec[p * 64 + grp];

    float ss[8];
#pragma unroll
    for (int r = 0; r < 8; ++r) {
        float t = 0.f;
#pragma unroll
        for (int p = 0; p < 4; ++p) {
            const float y = acc[p][r] + bias[p];
            acc[p][r] = y;
            t += y * y;
        }
        for (int off = 32; off; off >>= 1) t += __shfl_xor(t, off);
        ss[r] = t;
    }
    if (lane == 0) {
#pragma unroll
        for (int r = 0; r < 8; ++r) red[wave][r] = ss[r];
    }
    __syncthreads();

#pragma unroll
    for (int r = 0; r < 8; ++r) {
        const float s = 0.25f * (red[0][r] + red[1][r] + red[2][r] + red[3][r]);
        const float scale = 1.0f / fmaxf(sqrtf(s), 1e-12f);
        if (sub == 0) {
#pragma unroll
            for (int p = 0; p < 4; ++p)
                Yall[(size_t)(r0 + r) * ND + p * 64 + grp] = acc[p][r] * scale;
        }
    }
}

// ---------------------------------------------------------------------------
// Kernel 2: attn + exact top-10 at 320 blocks (one per (b,c)), 256 threads
// (R17 version, proven best). lax.top_k semantics: descending, lowest index
// on ties.
// ---------------------------------------------------------------------------
__global__ __launch_bounds__(256) void attn_topk_kernel(
    const float* __restrict__ cdd_p,
    const float* __restrict__ his_p,
    float* __restrict__ out_idx_f,
    int* __restrict__ ws_idx,
    float* __restrict__ ws_w)
{
    __shared__ float attn_s[128];
    const int bc  = blockIdx.x;            // b*NCDD + c
    const int b   = bc / NCDD;
    const int tid = threadIdx.x;
    const int sub = tid & 3, grp = tid >> 2;   // 64 groups
    const int wave = tid >> 6, lane = tid & 63;

    const float* __restrict__ crow = cdd_p + (size_t)bc * ND;
    const float* __restrict__ hbase = his_p + (size_t)b * NHIS * ND;
    {
        const int h0 = grp, h1 = grp + 64;
        const float* __restrict__ h0row = hbase + (size_t)h0 * ND;
        const float* __restrict__ h1row = hbase + (size_t)h1 * ND;
        float a0 = 0.f, a1 = 0.f;
#pragma unroll
        for (int i = 0; i < 16; ++i) {
            const int kb = sub * 4 + 16 * i;
            const float4 cv = *(const float4*)(crow + kb);
            const float4 v0 = *(const float4*)(h0row + kb);
            a0 += cv.x * v0.x + cv.y * v0.y + cv.z * v0.z + cv.w * v0.w;
            if (h1 < NHIS) {
                const float4 v1 = *(const float4*)(h1row + kb);
                a1 += cv.x * v1.x + cv.y * v1.y + cv.z * v1.z + cv.w * v1.w;
            }
        }
        a0 += __shfl_xor(a0, 1); a0 += __shfl_xor(a0, 2);
        a1 += __shfl_xor(a1, 1); a1 += __shfl_xor(a1, 2);
        if (sub == 0) {
            attn_s[h0] = a0;
            if (h1 < NHIS) attn_s[h1] = a1;
        }
    }
    __syncthreads();

    if (wave == 0) {
        float v0 = attn_s[lane];
        float v1 = (lane + 64 < NHIS) ? attn_s[lane + 64] : NEG_INF;
#pragma unroll
        for (int k = 0; k < NK; ++k) {
            float lv; int li;
            if (v1 > v0) { lv = v1; li = lane + 64; }
            else         { lv = v0; li = lane; }            // tie -> lower idx
            for (int off = 1; off < 64; off <<= 1) {
                const float ov = __shfl_xor(lv, off);
                const int   oi = __shfl_xor(li, off);
                if (ov > lv || (ov == lv && oi < li)) { lv = ov; li = oi; }
            }
            if (lane == 0) {
                const float w = (lv < THRESH) ? 0.0f : lv;
                const int g = bc * NK + k;
                ws_idx[g] = li;
                ws_w[g]   = w;
                out_idx_f[g] = (float)li;
            }
            if (li == lane)            v0 = NEG_INF;
            else if (li == lane + 64)  v1 = NEG_INF;
        }
    }
}

// ---------------------------------------------------------------------------
// Kernel 3: gather + scale — BYTE-IDENTICAL to R9 (calibrated ~103 us,
// ~92% of the demonstrated mixed-stream fabric ceiling).
// ---------------------------------------------------------------------------
__global__ __launch_bounds__(256) void gather_kernel(
    const float* __restrict__ his_emb,
    const int* __restrict__ ws_idx,
    const float* __restrict__ ws_w,
    float* __restrict__ out)
{
    const int orig = blockIdx.x;
    const int g = (orig & 7) * 400 + (orig >> 3);   // XCD-chunked (bijective)
    const int b = g / (NCDD * NK);
    const int tid = threadIdx.x;
    const float w = ws_w[g];

    f32x4* __restrict__ dst = (f32x4*)(out + (size_t)g * TLD);

    if (w == 0.0f) {
        const f32x4 z = {0.f, 0.f, 0.f, 0.f};
#pragma unroll
        for (int it = 0; it < 22; ++it) dst[tid + it * 256] = z;
        if (tid < 128) dst[22 * 256 + tid] = z;
        return;
    }

    const int idx = ws_idx[g];
    const f32x4* __restrict__ src =
        (const f32x4*)(his_emb + ((size_t)b * NHIS + idx) * TLD);

    f32x4 v[22];
    f32x4 vt;
#pragma unroll
    for (int j = 0; j < 22; ++j) v[j] = src[tid + j * 256];
    const bool tail = (tid < 128);
    if (tail) vt = src[22 * 256 + tid];

#pragma unroll
    for (int j = 0; j < 22; ++j) dst[tid + j * 256] = v[j] * w;
    if (tail) dst[22 * 256 + tid] = vt * w;
}

// ---------------------------------------------------------------------------
extern "C" void kernel_launch(void* const* d_in, const int* in_sizes, int n_in,
                              void* d_out, int out_size, void* d_ws, size_t ws_size,
                              hipStream_t stream)
{
    const float* cdd_repr = (const float*)d_in[0];   // (64,5,256)
    const float* his_repr = (const float*)d_in[1];   // (64,100,256)
    const float* his_emb  = (const float*)d_in[2];   // (64,100,30,3,256)
    const float* W_sel    = (const float*)d_in[3];   // (256,256)
    const float* b_sel    = (const float*)d_in[4];   // (256,)
    float* out = (float*)d_out;

    // Workspace layout
    char* ws = (char*)d_ws;
    float* Yall  = (float*)ws;                       // 6720 rows * 256 * 4
    float* his_p = Yall;                             // rows [0, 6400)
    float* cdd_p = Yall + (size_t)NROWS_HIS * ND;    // rows [6400, 6720)
    int*   idx_i = (int*)(ws + 6881280);             // 3200*4
    float* w_w   = (float*)(ws + 6894080);           // 3200*4

    // Output: his_activated [73,728,000] then idx [3200] (as float values)
    float* out_idx_f = out + (size_t)NB * NCDD * NK * TLD;

    proj_norm_all<<<(NROWS_HIS + NROWS_CDD) / 8, 256, 0, stream>>>(
        his_repr, cdd_repr, W_sel, b_sel, Yall);
    attn_topk_kernel<<<NB * NCDD, 256, 0, stream>>>(cdd_p, his_p,
                                                    out_idx_f, idx_i, w_w);
    gather_kernel<<<NB * NCDD * NK, 256, 0, stream>>>(his_emb, idx_i, w_w, out);
}